// Round 7
// baseline (272.859 us; speedup 1.0000x reference)
//
#include <hip/hip_runtime.h>
#include <cstdint>
#include <cstddef>

#define SEQ_LEN 256
#define BATCH 8
#define D_MODEL 768
#define D_STATE 64
#define HEADDIM 64
#define D_INNER 1536
#define NHEADS 24
#define CONV_CH 1664
#define D_IN_PROJ 3224
#define ZXLD 3328              // zx row stride (padded to 26*128)
#define ROWS (SEQ_LEN*BATCH)   // 2048

typedef float   f32x4 __attribute__((ext_vector_type(4)));
typedef _Float16 f16x8 __attribute__((ext_vector_type(8)));
typedef _Float16 f16x4 __attribute__((ext_vector_type(4)));

__device__ __forceinline__ float silu_f(float v) { return v / (1.f + __expf(-v)); }

__device__ __forceinline__ void gl_lds16(const _Float16* g, _Float16* l) {
  __builtin_amdgcn_global_load_lds(
      (const __attribute__((address_space(1))) unsigned int*)g,
      (__attribute__((address_space(3))) unsigned int*)l, 16, 0, 0);
}

// ---------------- fused pre-pass: cast seq->f16  +  transpose/cast both weights ----------------
#define CAST_BLKS 1536          // ROWS*D_MODEL/4/256
#define TW1_X 104               // ZXLD/32
#define TW1_BLKS (TW1_X*24)
#define TW2_X 24                // D_MODEL/32
#define TW2_BLKS (TW2_X*48)
__global__ __launch_bounds__(256) void pre_fused_kernel(
    const float* __restrict__ seq, _Float16* __restrict__ seqh,
    const float* __restrict__ W_in, _Float16* __restrict__ WinT,
    const float* __restrict__ W_out, _Float16* __restrict__ WoutT)
{
  __shared__ float tile[32][33];
  int bid = blockIdx.x;
  int tid = threadIdx.x;
  if (bid < CAST_BLKS) {
    int i = bid * 256 + tid;
    f32x4 v = ((const f32x4*)seq)[i];
    f16x4 o;
    o[0] = (_Float16)v[0]; o[1] = (_Float16)v[1];
    o[2] = (_Float16)v[2]; o[3] = (_Float16)v[3];
    ((f16x4*)seqh)[i] = o;
    return;
  }
  const float* in; _Float16* out; int R, C, Cpad, bx, by;
  if (bid < CAST_BLKS + TW1_BLKS) {
    int b2 = bid - CAST_BLKS;
    bx = b2 % TW1_X; by = b2 / TW1_X;
    in = W_in; out = WinT; R = D_MODEL; C = D_IN_PROJ; Cpad = ZXLD;
  } else {
    int b2 = bid - CAST_BLKS - TW1_BLKS;
    bx = b2 % TW2_X; by = b2 / TW2_X;
    in = W_out; out = WoutT; R = D_INNER; C = D_MODEL; Cpad = D_MODEL;
  }
  int c0 = bx * 32, r0 = by * 32;
  int tc = tid & 31, tr = tid >> 5;
#pragma unroll
  for (int i = 0; i < 4; i++) {
    int r = r0 + tr + i * 8, c = c0 + tc;
    tile[tr + i * 8][tc] = (r < R && c < C) ? in[(size_t)r * C + c] : 0.f;
  }
  __syncthreads();
#pragma unroll
  for (int i = 0; i < 4; i++) {
    int oc  = c0 + tr + i * 8;
    int orr = r0 + tc;
    if (oc < Cpad && orr < R) out[(size_t)oc * R + orr] = (_Float16)tile[tc][tr + i * 8];
  }
}

// ------------- f16 MFMA GEMM, m97-structure: global_load_lds + XOR swizzle (UNCHANGED) -------------
#define BKG 64
__global__ __launch_bounds__(256) void gemm_f16_glds(
    const _Float16* __restrict__ A, const _Float16* __restrict__ Bt,
    float* __restrict__ C, int M, int N, int K)
{
  __shared__ __align__(16) _Float16 As[128 * BKG];
  __shared__ __align__(16) _Float16 Bs[128 * BKG];
  int tid = threadIdx.x;
  int m0 = blockIdx.x * 128, n0 = blockIdx.y * 128;
  int wave = tid >> 6, lane = tid & 63;
  int wm = (wave >> 1) * 64, wn = (wave & 1) * 64;
  int lr = lane & 15, lk = lane >> 4;

  int srow[4], scol[4];
#pragma unroll
  for (int i = 0; i < 4; i++) {
    int o = wave * 4096 + i * 1024 + lane * 16;
    int row = o >> 7, cp = (o >> 4) & 7;
    srow[i] = row;
    scol[i] = (cp ^ (row & 7)) * 8;
  }

  f32x4 z4 = {0.f, 0.f, 0.f, 0.f};
  f32x4 acc[4][4];
#pragma unroll
  for (int i = 0; i < 4; i++)
#pragma unroll
    for (int j = 0; j < 4; j++) acc[i][j] = z4;

  for (int k0 = 0; k0 < K; k0 += BKG) {
#pragma unroll
    for (int i = 0; i < 4; i++) {
      gl_lds16(A  + (size_t)(m0 + srow[i]) * K + k0 + scol[i],
               As + wave * 2048 + i * 512);
      gl_lds16(Bt + (size_t)(n0 + srow[i]) * K + k0 + scol[i],
               Bs + wave * 2048 + i * 512);
    }
    __syncthreads();
#pragma unroll
    for (int kk = 0; kk < 2; kk++) {
      f16x8 af[4], bfv[4];
#pragma unroll
      for (int i = 0; i < 4; i++) {
        int row = wm + i * 16 + lr;
        int ch  = (kk * 4 + lk) ^ (row & 7);
        af[i] = *(const f16x8*)(As + row * BKG + ch * 8);
      }
#pragma unroll
      for (int j = 0; j < 4; j++) {
        int row = wn + j * 16 + lr;
        int ch  = (kk * 4 + lk) ^ (row & 7);
        bfv[j] = *(const f16x8*)(Bs + row * BKG + ch * 8);
      }
#pragma unroll
      for (int i = 0; i < 4; i++)
#pragma unroll
        for (int j = 0; j < 4; j++)
          acc[i][j] = __builtin_amdgcn_mfma_f32_16x16x32_f16(af[i], bfv[j], acc[i][j], 0, 0, 0);
    }
    __syncthreads();
  }
#pragma unroll
  for (int i = 0; i < 4; i++)
#pragma unroll
    for (int j = 0; j < 4; j++) {
      int col = n0 + wn + j * 16 + lr;
#pragma unroll
      for (int r = 0; r < 4; r++) {
        int row = m0 + wm + i * 16 + lk * 4 + r;
        C[(size_t)row * N + col] = acc[i][j][r];
      }
    }
}

// ---------------- prep v2: 8 rows/block, vectorized, conv consts cached in regs ----------------
// outputs coefX/dxX in f16.  chunk A: k=tid (x-chans 4k..4k+3); chunk B (tid<128): k=256+tid;
// BC (128<=tid<160): chunk j=tid-128 of the 128 B/C channels.
#define PREP_RPB 8
__global__ __launch_bounds__(256) void prep_kernel(
    const float* __restrict__ zx,      // ROWS x ZXLD
    const float* __restrict__ conv_w,  // 1664 x 4
    const float* __restrict__ conv_b,  // 1664
    const float* __restrict__ dt_bias, // 24
    const float* __restrict__ A_log,   // 24
    const float* __restrict__ Dp,      // 24
    float* __restrict__ siluBC,        // ROWS x 128
    _Float16* __restrict__ coefX,      // ROWS x 1536 (f16)
    _Float16* __restrict__ dxX,        // ROWS x 1536 (f16)
    float* __restrict__ dAr)           // ROWS x 24
{
  int r0 = blockIdx.x * PREP_RPB;
  int tid = threadIdx.x;
  __shared__ float sdtp[PREP_RPB][NHEADS];

  // phase 1: dt -> softplus, dA for all 8 rows
  if (tid < PREP_RPB * NHEADS) {
    int rr = tid / NHEADS, h = tid - rr * NHEADS;
    int r = r0 + rr;
    float dtr = zx[(size_t)r * ZXLD + D_INNER + CONV_CH + h] + dt_bias[h];
    float dtp = (dtr > 15.f) ? dtr : log1pf(__expf(dtr));
    sdtp[rr][h] = dtp;
    dAr[(size_t)r * NHEADS + h] = __expf(dtp * -__expf(A_log[h]));
  }

  // per-thread conv constants (loaded once per block)
  float wA[4], bA[4], DvA;
  int hA = tid >> 4;                       // head of chunk A (4*tid..4*tid+3 all in head tid>>4)
  DvA = Dp[hA];
#pragma unroll
  for (int q = 0; q < 4; q++) { int c = tid * 4 + q; wA[q] = conv_w[c * 4 + 3]; bA[q] = conv_b[c]; }
  float wBv[4], bBv[4], DvB = 0.f; int hB = 0;
  if (tid < 128) {
    hB = (256 + tid) >> 4; DvB = Dp[hB];
#pragma unroll
    for (int q = 0; q < 4; q++) { int c = (256 + tid) * 4 + q; wBv[q] = conv_w[c * 4 + 3]; bBv[q] = conv_b[c]; }
  }
  float wCv[4], bCv[4];
  if (tid >= 128 && tid < 160) {
#pragma unroll
    for (int q = 0; q < 4; q++) { int c = D_INNER + (tid - 128) * 4 + q; wCv[q] = conv_w[c * 4 + 3]; bCv[q] = conv_b[c]; }
  }
  __syncthreads();

  for (int rr = 0; rr < PREP_RPB; rr++) {
    int r = r0 + rr;
    const float* row = zx + (size_t)r * ZXLD;
    // chunk A (all threads): x channels 4*tid .. 4*tid+3
    {
      int k = tid;
      f32x4 v = *(const f32x4*)(row + D_INNER + k * 4);
      float dtp = sdtp[rr][hA];
      f16x4 co, dx;
#pragma unroll
      for (int q = 0; q < 4; q++) {
        float xv = silu_f(v[q] * wA[q] + bA[q]);
        co[q] = (_Float16)(dtp * xv);
        dx[q] = (_Float16)(DvA * xv);
      }
      *(f16x4*)(coefX + (size_t)r * D_INNER + k * 4) = co;
      *(f16x4*)(dxX   + (size_t)r * D_INNER + k * 4) = dx;
    }
    if (tid < 128) {   // chunk B: x channels 4*(256+tid)..
      int k = 256 + tid;
      f32x4 v = *(const f32x4*)(row + D_INNER + k * 4);
      float dtp = sdtp[rr][hB];
      f16x4 co, dx;
#pragma unroll
      for (int q = 0; q < 4; q++) {
        float xv = silu_f(v[q] * wBv[q] + bBv[q]);
        co[q] = (_Float16)(dtp * xv);
        dx[q] = (_Float16)(DvB * xv);
      }
      *(f16x4*)(coefX + (size_t)r * D_INNER + k * 4) = co;
      *(f16x4*)(dxX   + (size_t)r * D_INNER + k * 4) = dx;
    } else if (tid < 160) {  // B/C channels
      int j = tid - 128;
      f32x4 v = *(const f32x4*)(row + 2 * D_INNER + j * 4);
      f32x4 o;
#pragma unroll
      for (int q = 0; q < 4; q++) o[q] = silu_f(v[q] * wCv[q] + bCv[q]);
      *(f32x4*)(siluBC + (size_t)r * 128 + j * 4) = o;
    }
  }
}

// ---------------- scan: barrier-free, 2-deep register prefetch, nontemporal state stores ----------------
__global__ __launch_bounds__(256) void scan2_kernel(
    const float* __restrict__ siluBC,    // ROWS x 128  (B then C)
    const _Float16* __restrict__ coefX,  // ROWS x 1536 (f16)
    const float* __restrict__ dAr,       // ROWS x 24
    const _Float16* __restrict__ dxX,    // ROWS x 1536 (f16)
    float* __restrict__ states,          // ROWS x 24 x 64 x 64
    _Float16* __restrict__ y_raw)        // ROWS x D_INNER (f16)
{
  int g = blockIdx.x;
  int bh = g >> 2, qp = g & 3;
  int b = bh / NHEADS, hh = bh - b * NHEADS;
  int tid = threadIdx.x;
  int pp = tid >> 4, nq = tid & 15;
  int n0 = nq * 4;
  int p  = qp * 16 + pp;
  int chp = hh * HEADDIM + p;

  f32x4 h4 = {0.f, 0.f, 0.f, 0.f};

  f32x4 aB, aC, bB, bC;
  float aCo, adA, aDx, bCo, bdA, bDx;
  {
    int r = b;                          // t=0
    aB  = *(const f32x4*)(siluBC + (size_t)r * 128 + n0);
    aC  = *(const f32x4*)(siluBC + (size_t)r * 128 + 64 + n0);
    aCo = (float)coefX[(size_t)r * D_INNER + chp];
    adA = dAr[(size_t)r * NHEADS + hh];
    aDx = (float)dxX[(size_t)r * D_INNER + chp];
    r = BATCH + b;                      // t=1
    bB  = *(const f32x4*)(siluBC + (size_t)r * 128 + n0);
    bC  = *(const f32x4*)(siluBC + (size_t)r * 128 + 64 + n0);
    bCo = (float)coefX[(size_t)r * D_INNER + chp];
    bdA = dAr[(size_t)r * NHEADS + hh];
    bDx = (float)dxX[(size_t)r * D_INNER + chp];
  }

  for (int t = 0; t < SEQ_LEN; t += 2) {
    // even step: consume stage A, refill A for t+2
    {
      int r = t * BATCH + b;
#pragma unroll
      for (int q = 0; q < 4; q++) h4[q] = h4[q] * adA + aCo * aB[q];
      float* sp = states + ((size_t)r * NHEADS + hh) * 4096 + (size_t)p * 64 + n0;
      __builtin_nontemporal_store(h4, (f32x4*)sp);
      float acc = h4[0] * aC[0] + h4[1] * aC[1] + h4[2] * aC[2] + h4[3] * aC[3];
      acc += __shfl_xor(acc, 1);
      acc += __shfl_xor(acc, 2);
      acc += __shfl_xor(acc, 4);
      acc += __shfl_xor(acc, 8);
      if (nq == 0) y_raw[(size_t)r * D_INNER + chp] = (_Float16)(acc + aDx);
      if (t + 2 < SEQ_LEN) {
        int rn = (t + 2) * BATCH + b;
        aB  = *(const f32x4*)(siluBC + (size_t)rn * 128 + n0);
        aC  = *(const f32x4*)(siluBC + (size_t)rn * 128 + 64 + n0);
        aCo = (float)coefX[(size_t)rn * D_INNER + chp];
        adA = dAr[(size_t)rn * NHEADS + hh];
        aDx = (float)dxX[(size_t)rn * D_INNER + chp];
      }
    }
    // odd step: consume stage B, refill B for t+3
    {
      int r = (t + 1) * BATCH + b;
#pragma unroll
      for (int q = 0; q < 4; q++) h4[q] = h4[q] * bdA + bCo * bB[q];
      float* sp = states + ((size_t)r * NHEADS + hh) * 4096 + (size_t)p * 64 + n0;
      __builtin_nontemporal_store(h4, (f32x4*)sp);
      float acc = h4[0] * bC[0] + h4[1] * bC[1] + h4[2] * bC[2] + h4[3] * bC[3];
      acc += __shfl_xor(acc, 1);
      acc += __shfl_xor(acc, 2);
      acc += __shfl_xor(acc, 4);
      acc += __shfl_xor(acc, 8);
      if (nq == 0) y_raw[(size_t)r * D_INNER + chp] = (_Float16)(acc + bDx);
      if (t + 3 < SEQ_LEN) {
        int rn = (t + 3) * BATCH + b;
        bB  = *(const f32x4*)(siluBC + (size_t)rn * 128 + n0);
        bC  = *(const f32x4*)(siluBC + (size_t)rn * 128 + 64 + n0);
        bCo = (float)coefX[(size_t)rn * D_INNER + chp];
        bdA = dAr[(size_t)rn * NHEADS + hh];
        bDx = (float)dxX[(size_t)rn * D_INNER + chp];
      }
    }
  }
}

// ---------------- gate (silu(z)) + RMSNorm + cast to f16, vectorized ----------------
// chunk A: k=tid (chans 4k..4k+3); chunk B (tid<128): k=256+tid.
__global__ __launch_bounds__(256) void gate_norm_kernel(
    const float* __restrict__ zx, const _Float16* __restrict__ y_raw,
    const float* __restrict__ norm_w, _Float16* __restrict__ yh)
{
  int r = blockIdx.x;
  int tid = threadIdx.x;
  const float* z = zx + (size_t)r * ZXLD;
  const _Float16* y = y_raw + (size_t)r * D_INNER;

  float vA[4], vB[4];
  float ss = 0.f;
  {
    f32x4 zv = *(const f32x4*)(z + tid * 4);
    f16x4 yv = *(const f16x4*)(y + tid * 4);
#pragma unroll
    for (int q = 0; q < 4; q++) {
      float w = (float)yv[q] * silu_f(zv[q]);
      vA[q] = w; ss += w * w;
    }
  }
  if (tid < 128) {
    int k = 256 + tid;
    f32x4 zv = *(const f32x4*)(z + k * 4);
    f16x4 yv = *(const f16x4*)(y + k * 4);
#pragma unroll
    for (int q = 0; q < 4; q++) {
      float w = (float)yv[q] * silu_f(zv[q]);
      vB[q] = w; ss += w * w;
    }
  }
#pragma unroll
  for (int o = 32; o > 0; o >>= 1) ss += __shfl_xor(ss, o);
  __shared__ float red[4];
  if ((tid & 63) == 0) red[tid >> 6] = ss;
  __syncthreads();
  float tot = red[0] + red[1] + red[2] + red[3];
  float scale = rsqrtf(tot / (float)D_INNER + 1e-5f);

  {
    f32x4 nw = *(const f32x4*)(norm_w + tid * 4);
    f16x4 o;
#pragma unroll
    for (int q = 0; q < 4; q++) o[q] = (_Float16)(vA[q] * scale * nw[q]);
    *(f16x4*)(yh + (size_t)r * D_INNER + tid * 4) = o;
  }
  if (tid < 128) {
    int k = 256 + tid;
    f32x4 nw = *(const f32x4*)(norm_w + k * 4);
    f16x4 o;
#pragma unroll
    for (int q = 0; q < 4; q++) o[q] = (_Float16)(vB[q] * scale * nw[q]);
    *(f16x4*)(yh + (size_t)r * D_INNER + k * 4) = o;
  }
}

extern "C" void kernel_launch(void* const* d_in, const int* in_sizes, int n_in,
                              void* d_out, int out_size, void* d_ws, size_t ws_size,
                              hipStream_t stream)
{
  (void)in_sizes; (void)n_in; (void)out_size; (void)ws_size;
  const float* seq     = (const float*)d_in[0];
  const float* W_in    = (const float*)d_in[1];
  const float* conv_w  = (const float*)d_in[2];
  const float* conv_b  = (const float*)d_in[3];
  const float* dt_bias = (const float*)d_in[4];
  const float* A_log   = (const float*)d_in[5];
  const float* Dp      = (const float*)d_in[6];
  const float* norm_w  = (const float*)d_in[7];
  const float* W_out   = (const float*)d_in[8];

  float* out    = (float*)d_out;                                  // (256,8,768)
  float* states = out + (size_t)SEQ_LEN * BATCH * D_MODEL;        // (256,8,24,64,64)

  char* ws = (char*)d_ws;
  size_t off = 0;
  auto alloc = [&](size_t bytes) -> void* {
    void* p = ws + off;
    off = (off + bytes + 255) & ~(size_t)255;
    return p;
  };
  float*    zx     = (float*)   alloc((size_t)ROWS * ZXLD * 4);
  _Float16* y_raw  = (_Float16*)alloc((size_t)ROWS * D_INNER * 2);
  _Float16* seqh   = (_Float16*)alloc((size_t)ROWS * D_MODEL * 2);
  _Float16* WinT   = (_Float16*)alloc((size_t)ZXLD * D_MODEL * 2);
  _Float16* WoutT  = (_Float16*)alloc((size_t)D_MODEL * D_INNER * 2);
  _Float16* yh     = (_Float16*)alloc((size_t)ROWS * D_INNER * 2);
  float*    siluBC = (float*)   alloc((size_t)ROWS * 128 * 4);
  _Float16* coefX  = (_Float16*)alloc((size_t)ROWS * D_INNER * 2);
  _Float16* dxX    = (_Float16*)alloc((size_t)ROWS * D_INNER * 2);
  float*    dAr    = (float*)   alloc((size_t)ROWS * NHEADS * 4);

  // 1) fused cast + transposes (one dispatch, fully parallel)
  pre_fused_kernel<<<CAST_BLKS + TW1_BLKS + TW2_BLKS, 256, 0, stream>>>(
      seq, seqh, W_in, WinT, W_out, WoutT);

  // 2) in-projection GEMM: zx = seq @ W_in   (M=2048, N=3328(pad), K=768)
  gemm_f16_glds<<<dim3(ROWS / 128, ZXLD / 128), 256, 0, stream>>>(
      seqh, WinT, zx, ROWS, ZXLD, D_MODEL);

  // 3) prep (parallel activations + per-step scalars)
  prep_kernel<<<ROWS / PREP_RPB, 256, 0, stream>>>(
      zx, conv_w, conv_b, dt_bias, A_log, Dp, siluBC, coefX, dxX, dAr);

  // 4) barrier-free scan (writes all states + raw y)
  scan2_kernel<<<BATCH * NHEADS * 4, 256, 0, stream>>>(
      siluBC, coefX, dAr, dxX, states, y_raw);

  // 5) gate + RMSNorm -> f16
  gate_norm_kernel<<<ROWS, 256, 0, stream>>>(zx, y_raw, norm_w, yh);

  // 6) out-projection GEMM: out = yh @ W_out  (M=2048, N=768, K=1536)
  gemm_f16_glds<<<dim3(ROWS / 128, D_MODEL / 128), 256, 0, stream>>>(
      yh, WoutT, out, ROWS, D_MODEL, D_INNER);
}

// Round 8
// 269.637 us; speedup vs baseline: 1.0120x; 1.0120x over previous
//
#include <hip/hip_runtime.h>
#include <cstdint>
#include <cstddef>

#define SEQ_LEN 256
#define BATCH 8
#define D_MODEL 768
#define D_STATE 64
#define HEADDIM 64
#define D_INNER 1536
#define NHEADS 24
#define CONV_CH 1664
#define D_IN_PROJ 3224
#define ZXLD 3328              // zx row stride (padded to 26*128)
#define ROWS (SEQ_LEN*BATCH)   // 2048

typedef float   f32x4 __attribute__((ext_vector_type(4)));
typedef _Float16 f16x8 __attribute__((ext_vector_type(8)));
typedef _Float16 f16x4 __attribute__((ext_vector_type(4)));

__device__ __forceinline__ float silu_f(float v) { return v / (1.f + __expf(-v)); }

__device__ __forceinline__ void gl_lds16(const _Float16* g, _Float16* l) {
  __builtin_amdgcn_global_load_lds(
      (const __attribute__((address_space(1))) unsigned int*)g,
      (__attribute__((address_space(3))) unsigned int*)l, 16, 0, 0);
}

// ---------------- fused pre-pass: cast seq->f16  +  transpose/cast both weights ----------------
#define CAST_BLKS 1536          // ROWS*D_MODEL/4/256
#define TW1_X 104               // ZXLD/32
#define TW1_BLKS (TW1_X*24)
#define TW2_X 24                // D_MODEL/32
#define TW2_BLKS (TW2_X*48)
__global__ __launch_bounds__(256) void pre_fused_kernel(
    const float* __restrict__ seq, _Float16* __restrict__ seqh,
    const float* __restrict__ W_in, _Float16* __restrict__ WinT,
    const float* __restrict__ W_out, _Float16* __restrict__ WoutT)
{
  __shared__ float tile[32][33];
  int bid = blockIdx.x;
  int tid = threadIdx.x;
  if (bid < CAST_BLKS) {
    int i = bid * 256 + tid;
    f32x4 v = ((const f32x4*)seq)[i];
    f16x4 o;
    o[0] = (_Float16)v[0]; o[1] = (_Float16)v[1];
    o[2] = (_Float16)v[2]; o[3] = (_Float16)v[3];
    ((f16x4*)seqh)[i] = o;
    return;
  }
  const float* in; _Float16* out; int R, C, Cpad, bx, by;
  if (bid < CAST_BLKS + TW1_BLKS) {
    int b2 = bid - CAST_BLKS;
    bx = b2 % TW1_X; by = b2 / TW1_X;
    in = W_in; out = WinT; R = D_MODEL; C = D_IN_PROJ; Cpad = ZXLD;
  } else {
    int b2 = bid - CAST_BLKS - TW1_BLKS;
    bx = b2 % TW2_X; by = b2 / TW2_X;
    in = W_out; out = WoutT; R = D_INNER; C = D_MODEL; Cpad = D_MODEL;
  }
  int c0 = bx * 32, r0 = by * 32;
  int tc = tid & 31, tr = tid >> 5;
#pragma unroll
  for (int i = 0; i < 4; i++) {
    int r = r0 + tr + i * 8, c = c0 + tc;
    tile[tr + i * 8][tc] = (r < R && c < C) ? in[(size_t)r * C + c] : 0.f;
  }
  __syncthreads();
#pragma unroll
  for (int i = 0; i < 4; i++) {
    int oc  = c0 + tr + i * 8;
    int orr = r0 + tc;
    if (oc < Cpad && orr < R) out[(size_t)oc * R + orr] = (_Float16)tile[tc][tr + i * 8];
  }
}

// ------------- f16 MFMA GEMM, m97-structure: global_load_lds + XOR swizzle (UNCHANGED) -------------
#define BKG 64
__global__ __launch_bounds__(256) void gemm_f16_glds(
    const _Float16* __restrict__ A, const _Float16* __restrict__ Bt,
    float* __restrict__ C, int M, int N, int K)
{
  __shared__ __align__(16) _Float16 As[128 * BKG];
  __shared__ __align__(16) _Float16 Bs[128 * BKG];
  int tid = threadIdx.x;
  int m0 = blockIdx.x * 128, n0 = blockIdx.y * 128;
  int wave = tid >> 6, lane = tid & 63;
  int wm = (wave >> 1) * 64, wn = (wave & 1) * 64;
  int lr = lane & 15, lk = lane >> 4;

  int srow[4], scol[4];
#pragma unroll
  for (int i = 0; i < 4; i++) {
    int o = wave * 4096 + i * 1024 + lane * 16;
    int row = o >> 7, cp = (o >> 4) & 7;
    srow[i] = row;
    scol[i] = (cp ^ (row & 7)) * 8;
  }

  f32x4 z4 = {0.f, 0.f, 0.f, 0.f};
  f32x4 acc[4][4];
#pragma unroll
  for (int i = 0; i < 4; i++)
#pragma unroll
    for (int j = 0; j < 4; j++) acc[i][j] = z4;

  for (int k0 = 0; k0 < K; k0 += BKG) {
#pragma unroll
    for (int i = 0; i < 4; i++) {
      gl_lds16(A  + (size_t)(m0 + srow[i]) * K + k0 + scol[i],
               As + wave * 2048 + i * 512);
      gl_lds16(Bt + (size_t)(n0 + srow[i]) * K + k0 + scol[i],
               Bs + wave * 2048 + i * 512);
    }
    __syncthreads();
#pragma unroll
    for (int kk = 0; kk < 2; kk++) {
      f16x8 af[4], bfv[4];
#pragma unroll
      for (int i = 0; i < 4; i++) {
        int row = wm + i * 16 + lr;
        int ch  = (kk * 4 + lk) ^ (row & 7);
        af[i] = *(const f16x8*)(As + row * BKG + ch * 8);
      }
#pragma unroll
      for (int j = 0; j < 4; j++) {
        int row = wn + j * 16 + lr;
        int ch  = (kk * 4 + lk) ^ (row & 7);
        bfv[j] = *(const f16x8*)(Bs + row * BKG + ch * 8);
      }
#pragma unroll
      for (int i = 0; i < 4; i++)
#pragma unroll
        for (int j = 0; j < 4; j++)
          acc[i][j] = __builtin_amdgcn_mfma_f32_16x16x32_f16(af[i], bfv[j], acc[i][j], 0, 0, 0);
    }
    __syncthreads();
  }
#pragma unroll
  for (int i = 0; i < 4; i++)
#pragma unroll
    for (int j = 0; j < 4; j++) {
      int col = n0 + wn + j * 16 + lr;
#pragma unroll
      for (int r = 0; r < 4; r++) {
        int row = m0 + wm + i * 16 + lk * 4 + r;
        C[(size_t)row * N + col] = acc[i][j][r];
      }
    }
}

// ---------------- prep (r6 structure): one block per row; coefX/dxX now f16 ----------------
__global__ __launch_bounds__(256) void prep_kernel(
    const float* __restrict__ zx,      // ROWS x ZXLD
    const float* __restrict__ conv_w,  // 1664 x 4
    const float* __restrict__ conv_b,  // 1664
    const float* __restrict__ dt_bias, // 24
    const float* __restrict__ A_log,   // 24
    const float* __restrict__ Dp,      // 24
    float* __restrict__ siluBC,        // ROWS x 128
    _Float16* __restrict__ coefX,      // ROWS x 1536 (f16)
    _Float16* __restrict__ dxX,        // ROWS x 1536 (f16)
    float* __restrict__ dAr)           // ROWS x 24
{
  int r = blockIdx.x;
  int tid = threadIdx.x;
  const float* row = zx + (size_t)r * ZXLD;
  __shared__ float sdtp[NHEADS];
  if (tid < NHEADS) {
    float dtr = row[D_INNER + CONV_CH + tid] + dt_bias[tid];
    float dtp = (dtr > 15.f) ? dtr : log1pf(__expf(dtr));
    sdtp[tid] = dtp;
    float Ar = -__expf(A_log[tid]);
    dAr[(size_t)r * NHEADS + tid] = __expf(dtp * Ar);
  }
  if (tid < 128) {
    int ch = D_INNER + tid;   // conv channel 1536..1663
    float v = row[2 * D_INNER + tid] * conv_w[ch * 4 + 3] + conv_b[ch];
    siluBC[(size_t)r * 128 + tid] = silu_f(v);
  }
  __syncthreads();
#pragma unroll
  for (int i = 0; i < 6; i++) {
    int c = tid + i * 256;           // 0..1535
    float xv = silu_f(row[D_INNER + c] * conv_w[c * 4 + 3] + conv_b[c]);
    int h = c >> 6;
    coefX[(size_t)r * D_INNER + c] = (_Float16)(sdtp[h] * xv);
    dxX[(size_t)r * D_INNER + c]  = (_Float16)(Dp[h] * xv);
  }
}

// ---------------- scan: barrier-free, 2-deep register prefetch, nontemporal state stores ----------------
__global__ __launch_bounds__(256) void scan2_kernel(
    const float* __restrict__ siluBC,    // ROWS x 128  (B then C)
    const _Float16* __restrict__ coefX,  // ROWS x 1536 (f16)
    const float* __restrict__ dAr,       // ROWS x 24
    const _Float16* __restrict__ dxX,    // ROWS x 1536 (f16)
    float* __restrict__ states,          // ROWS x 24 x 64 x 64
    float* __restrict__ y_raw)           // ROWS x D_INNER (f32)
{
  int g = blockIdx.x;
  int bh = g >> 2, qp = g & 3;
  int b = bh / NHEADS, hh = bh - b * NHEADS;
  int tid = threadIdx.x;
  int pp = tid >> 4, nq = tid & 15;
  int n0 = nq * 4;
  int p  = qp * 16 + pp;
  int chp = hh * HEADDIM + p;

  f32x4 h4 = {0.f, 0.f, 0.f, 0.f};

  f32x4 aB, aC, bB, bC;
  float aCo, adA, aDx, bCo, bdA, bDx;
  {
    int r = b;                          // t=0
    aB  = *(const f32x4*)(siluBC + (size_t)r * 128 + n0);
    aC  = *(const f32x4*)(siluBC + (size_t)r * 128 + 64 + n0);
    aCo = (float)coefX[(size_t)r * D_INNER + chp];
    adA = dAr[(size_t)r * NHEADS + hh];
    aDx = (float)dxX[(size_t)r * D_INNER + chp];
    r = BATCH + b;                      // t=1
    bB  = *(const f32x4*)(siluBC + (size_t)r * 128 + n0);
    bC  = *(const f32x4*)(siluBC + (size_t)r * 128 + 64 + n0);
    bCo = (float)coefX[(size_t)r * D_INNER + chp];
    bdA = dAr[(size_t)r * NHEADS + hh];
    bDx = (float)dxX[(size_t)r * D_INNER + chp];
  }

  for (int t = 0; t < SEQ_LEN; t += 2) {
    // even step: consume stage A, refill A for t+2
    {
      int r = t * BATCH + b;
#pragma unroll
      for (int q = 0; q < 4; q++) h4[q] = h4[q] * adA + aCo * aB[q];
      float* sp = states + ((size_t)r * NHEADS + hh) * 4096 + (size_t)p * 64 + n0;
      __builtin_nontemporal_store(h4, (f32x4*)sp);
      float acc = h4[0] * aC[0] + h4[1] * aC[1] + h4[2] * aC[2] + h4[3] * aC[3];
      acc += __shfl_xor(acc, 1);
      acc += __shfl_xor(acc, 2);
      acc += __shfl_xor(acc, 4);
      acc += __shfl_xor(acc, 8);
      if (nq == 0) y_raw[(size_t)r * D_INNER + chp] = acc + aDx;
      if (t + 2 < SEQ_LEN) {
        int rn = (t + 2) * BATCH + b;
        aB  = *(const f32x4*)(siluBC + (size_t)rn * 128 + n0);
        aC  = *(const f32x4*)(siluBC + (size_t)rn * 128 + 64 + n0);
        aCo = (float)coefX[(size_t)rn * D_INNER + chp];
        adA = dAr[(size_t)rn * NHEADS + hh];
        aDx = (float)dxX[(size_t)rn * D_INNER + chp];
      }
    }
    // odd step: consume stage B, refill B for t+3
    {
      int r = (t + 1) * BATCH + b;
#pragma unroll
      for (int q = 0; q < 4; q++) h4[q] = h4[q] * bdA + bCo * bB[q];
      float* sp = states + ((size_t)r * NHEADS + hh) * 4096 + (size_t)p * 64 + n0;
      __builtin_nontemporal_store(h4, (f32x4*)sp);
      float acc = h4[0] * bC[0] + h4[1] * bC[1] + h4[2] * bC[2] + h4[3] * bC[3];
      acc += __shfl_xor(acc, 1);
      acc += __shfl_xor(acc, 2);
      acc += __shfl_xor(acc, 4);
      acc += __shfl_xor(acc, 8);
      if (nq == 0) y_raw[(size_t)r * D_INNER + chp] = acc + bDx;
      if (t + 3 < SEQ_LEN) {
        int rn = (t + 3) * BATCH + b;
        bB  = *(const f32x4*)(siluBC + (size_t)rn * 128 + n0);
        bC  = *(const f32x4*)(siluBC + (size_t)rn * 128 + 64 + n0);
        bCo = (float)coefX[(size_t)rn * D_INNER + chp];
        bdA = dAr[(size_t)rn * NHEADS + hh];
        bDx = (float)dxX[(size_t)rn * D_INNER + chp];
      }
    }
  }
}

// ---------------- gate (silu(z)) + RMSNorm + cast to f16 (r6 structure) ----------------
__global__ __launch_bounds__(256) void gate_norm_kernel(
    const float* __restrict__ zx, const float* __restrict__ y_raw,
    const float* __restrict__ norm_w, _Float16* __restrict__ yh)
{
  int r = blockIdx.x;
  const float* z = zx + (size_t)r * ZXLD;
  const float* y = y_raw + (size_t)r * D_INNER;
  float v[6];
  float ss = 0.f;
#pragma unroll
  for (int i = 0; i < 6; i++) {
    int c = threadIdx.x + i * 256;
    float w = y[c] * silu_f(z[c]);
    v[i] = w;
    ss += w * w;
  }
#pragma unroll
  for (int o = 32; o > 0; o >>= 1) ss += __shfl_xor(ss, o);
  __shared__ float red[4];
  if ((threadIdx.x & 63) == 0) red[threadIdx.x >> 6] = ss;
  __syncthreads();
  float tot = red[0] + red[1] + red[2] + red[3];
  float scale = rsqrtf(tot / (float)D_INNER + 1e-5f);
#pragma unroll
  for (int i = 0; i < 6; i++) {
    int c = threadIdx.x + i * 256;
    yh[(size_t)r * D_INNER + c] = (_Float16)(v[i] * scale * norm_w[c]);
  }
}

extern "C" void kernel_launch(void* const* d_in, const int* in_sizes, int n_in,
                              void* d_out, int out_size, void* d_ws, size_t ws_size,
                              hipStream_t stream)
{
  (void)in_sizes; (void)n_in; (void)out_size; (void)ws_size;
  const float* seq     = (const float*)d_in[0];
  const float* W_in    = (const float*)d_in[1];
  const float* conv_w  = (const float*)d_in[2];
  const float* conv_b  = (const float*)d_in[3];
  const float* dt_bias = (const float*)d_in[4];
  const float* A_log   = (const float*)d_in[5];
  const float* Dp      = (const float*)d_in[6];
  const float* norm_w  = (const float*)d_in[7];
  const float* W_out   = (const float*)d_in[8];

  float* out    = (float*)d_out;                                  // (256,8,768)
  float* states = out + (size_t)SEQ_LEN * BATCH * D_MODEL;        // (256,8,24,64,64)

  char* ws = (char*)d_ws;
  size_t off = 0;
  auto alloc = [&](size_t bytes) -> void* {
    void* p = ws + off;
    off = (off + bytes + 255) & ~(size_t)255;
    return p;
  };
  float*    zx     = (float*)   alloc((size_t)ROWS * ZXLD * 4);
  float*    y_raw  = (float*)   alloc((size_t)ROWS * D_INNER * 4);
  _Float16* seqh   = (_Float16*)alloc((size_t)ROWS * D_MODEL * 2);
  _Float16* WinT   = (_Float16*)alloc((size_t)ZXLD * D_MODEL * 2);
  _Float16* WoutT  = (_Float16*)alloc((size_t)D_MODEL * D_INNER * 2);
  _Float16* yh     = (_Float16*)alloc((size_t)ROWS * D_INNER * 2);
  float*    siluBC = (float*)   alloc((size_t)ROWS * 128 * 4);
  _Float16* coefX  = (_Float16*)alloc((size_t)ROWS * D_INNER * 2);
  _Float16* dxX    = (_Float16*)alloc((size_t)ROWS * D_INNER * 2);
  float*    dAr    = (float*)   alloc((size_t)ROWS * NHEADS * 4);

  // 1) fused cast + transposes (one dispatch, fully parallel)
  pre_fused_kernel<<<CAST_BLKS + TW1_BLKS + TW2_BLKS, 256, 0, stream>>>(
      seq, seqh, W_in, WinT, W_out, WoutT);

  // 2) in-projection GEMM: zx = seq @ W_in   (M=2048, N=3328(pad), K=768)
  gemm_f16_glds<<<dim3(ROWS / 128, ZXLD / 128), 256, 0, stream>>>(
      seqh, WinT, zx, ROWS, ZXLD, D_MODEL);

  // 3) prep (parallel activations + per-step scalars)
  prep_kernel<<<ROWS, 256, 0, stream>>>(
      zx, conv_w, conv_b, dt_bias, A_log, Dp, siluBC, coefX, dxX, dAr);

  // 4) barrier-free scan (writes all states + raw y)
  scan2_kernel<<<BATCH * NHEADS * 4, 256, 0, stream>>>(
      siluBC, coefX, dAr, dxX, states, y_raw);

  // 5) gate + RMSNorm -> f16
  gate_norm_kernel<<<ROWS, 256, 0, stream>>>(zx, y_raw, norm_w, yh);

  // 6) out-projection GEMM: out = yh @ W_out  (M=2048, N=768, K=1536)
  gemm_f16_glds<<<dim3(ROWS / 128, D_MODEL / 128), 256, 0, stream>>>(
      yh, WoutT, out, ROWS, D_MODEL, D_INNER);
}

// Round 9
// 210.646 us; speedup vs baseline: 1.2953x; 1.2800x over previous
//
#include <hip/hip_runtime.h>
#include <cstdint>
#include <cstddef>

#define SEQ_LEN 256
#define BATCH 8
#define D_MODEL 768
#define D_STATE 64
#define HEADDIM 64
#define D_INNER 1536
#define NHEADS 24
#define CONV_CH 1664
#define D_IN_PROJ 3224
#define ZXLD 3328              // zx row stride (padded to 26*128)
#define ROWS (SEQ_LEN*BATCH)   // 2048

typedef float   f32x4 __attribute__((ext_vector_type(4)));
typedef _Float16 f16x8 __attribute__((ext_vector_type(8)));
typedef _Float16 f16x4 __attribute__((ext_vector_type(4)));

__device__ __forceinline__ float silu_f(float v) { return v / (1.f + __expf(-v)); }

__device__ __forceinline__ void gl_lds16(const _Float16* g, _Float16* l) {
  __builtin_amdgcn_global_load_lds(
      (const __attribute__((address_space(1))) unsigned int*)g,
      (__attribute__((address_space(3))) unsigned int*)l, 16, 0, 0);
}

// ---------------- fused pre-pass: cast seq->f16  +  transpose/cast both weights ----------------
#define CAST_BLKS 1536          // ROWS*D_MODEL/4/256
#define TW1_X 104               // ZXLD/32
#define TW1_BLKS (TW1_X*24)
#define TW2_X 24                // D_MODEL/32
#define TW2_BLKS (TW2_X*48)
__global__ __launch_bounds__(256) void pre_fused_kernel(
    const float* __restrict__ seq, _Float16* __restrict__ seqh,
    const float* __restrict__ W_in, _Float16* __restrict__ WinT,
    const float* __restrict__ W_out, _Float16* __restrict__ WoutT)
{
  __shared__ float tile[32][33];
  int bid = blockIdx.x;
  int tid = threadIdx.x;
  if (bid < CAST_BLKS) {
    int i = bid * 256 + tid;
    f32x4 v = ((const f32x4*)seq)[i];
    f16x4 o;
    o[0] = (_Float16)v[0]; o[1] = (_Float16)v[1];
    o[2] = (_Float16)v[2]; o[3] = (_Float16)v[3];
    ((f16x4*)seqh)[i] = o;
    return;
  }
  const float* in; _Float16* out; int R, C, Cpad, bx, by;
  if (bid < CAST_BLKS + TW1_BLKS) {
    int b2 = bid - CAST_BLKS;
    bx = b2 % TW1_X; by = b2 / TW1_X;
    in = W_in; out = WinT; R = D_MODEL; C = D_IN_PROJ; Cpad = ZXLD;
  } else {
    int b2 = bid - CAST_BLKS - TW1_BLKS;
    bx = b2 % TW2_X; by = b2 / TW2_X;
    in = W_out; out = WoutT; R = D_INNER; C = D_MODEL; Cpad = D_MODEL;
  }
  int c0 = bx * 32, r0 = by * 32;
  int tc = tid & 31, tr = tid >> 5;
#pragma unroll
  for (int i = 0; i < 4; i++) {
    int r = r0 + tr + i * 8, c = c0 + tc;
    tile[tr + i * 8][tc] = (r < R && c < C) ? in[(size_t)r * C + c] : 0.f;
  }
  __syncthreads();
#pragma unroll
  for (int i = 0; i < 4; i++) {
    int oc  = c0 + tr + i * 8;
    int orr = r0 + tc;
    if (oc < Cpad && orr < R) out[(size_t)oc * R + orr] = (_Float16)tile[tc][tr + i * 8];
  }
}

// ------------- f16 MFMA GEMM, m97-structure: global_load_lds + XOR swizzle (UNCHANGED) -------------
#define BKG 64
__global__ __launch_bounds__(256) void gemm_f16_glds(
    const _Float16* __restrict__ A, const _Float16* __restrict__ Bt,
    float* __restrict__ C, int M, int N, int K)
{
  __shared__ __align__(16) _Float16 As[128 * BKG];
  __shared__ __align__(16) _Float16 Bs[128 * BKG];
  int tid = threadIdx.x;
  int m0 = blockIdx.x * 128, n0 = blockIdx.y * 128;
  int wave = tid >> 6, lane = tid & 63;
  int wm = (wave >> 1) * 64, wn = (wave & 1) * 64;
  int lr = lane & 15, lk = lane >> 4;

  int srow[4], scol[4];
#pragma unroll
  for (int i = 0; i < 4; i++) {
    int o = wave * 4096 + i * 1024 + lane * 16;
    int row = o >> 7, cp = (o >> 4) & 7;
    srow[i] = row;
    scol[i] = (cp ^ (row & 7)) * 8;
  }

  f32x4 z4 = {0.f, 0.f, 0.f, 0.f};
  f32x4 acc[4][4];
#pragma unroll
  for (int i = 0; i < 4; i++)
#pragma unroll
    for (int j = 0; j < 4; j++) acc[i][j] = z4;

  for (int k0 = 0; k0 < K; k0 += BKG) {
#pragma unroll
    for (int i = 0; i < 4; i++) {
      gl_lds16(A  + (size_t)(m0 + srow[i]) * K + k0 + scol[i],
               As + wave * 2048 + i * 512);
      gl_lds16(Bt + (size_t)(n0 + srow[i]) * K + k0 + scol[i],
               Bs + wave * 2048 + i * 512);
    }
    __syncthreads();
#pragma unroll
    for (int kk = 0; kk < 2; kk++) {
      f16x8 af[4], bfv[4];
#pragma unroll
      for (int i = 0; i < 4; i++) {
        int row = wm + i * 16 + lr;
        int ch  = (kk * 4 + lk) ^ (row & 7);
        af[i] = *(const f16x8*)(As + row * BKG + ch * 8);
      }
#pragma unroll
      for (int j = 0; j < 4; j++) {
        int row = wn + j * 16 + lr;
        int ch  = (kk * 4 + lk) ^ (row & 7);
        bfv[j] = *(const f16x8*)(Bs + row * BKG + ch * 8);
      }
#pragma unroll
      for (int i = 0; i < 4; i++)
#pragma unroll
        for (int j = 0; j < 4; j++)
          acc[i][j] = __builtin_amdgcn_mfma_f32_16x16x32_f16(af[i], bfv[j], acc[i][j], 0, 0, 0);
    }
    __syncthreads();
  }
#pragma unroll
  for (int i = 0; i < 4; i++)
#pragma unroll
    for (int j = 0; j < 4; j++) {
      int col = n0 + wn + j * 16 + lr;
#pragma unroll
      for (int r = 0; r < 4; r++) {
        int row = m0 + wm + i * 16 + lk * 4 + r;
        C[(size_t)row * N + col] = acc[i][j][r];
      }
    }
}

// ---------------- prep: precompute silu'd B/C, coef = dtp*silu(x), dx = D*silu(x), dA ----------------
// (all f32 intermediates — r7/r8 proved f16 coefX/dxX regresses +59us, mechanism unexplained)
__global__ __launch_bounds__(256) void prep_kernel(
    const float* __restrict__ zx,      // ROWS x ZXLD
    const float* __restrict__ conv_w,  // 1664 x 4
    const float* __restrict__ conv_b,  // 1664
    const float* __restrict__ dt_bias, // 24
    const float* __restrict__ A_log,   // 24
    const float* __restrict__ Dp,      // 24
    float* __restrict__ siluBC,        // ROWS x 128
    float* __restrict__ coefX,         // ROWS x 1536
    float* __restrict__ dxX,           // ROWS x 1536
    float* __restrict__ dAr)           // ROWS x 24
{
  int r = blockIdx.x;
  int tid = threadIdx.x;
  const float* row = zx + (size_t)r * ZXLD;
  __shared__ float sdtp[NHEADS];
  if (tid < NHEADS) {
    float dtr = row[D_INNER + CONV_CH + tid] + dt_bias[tid];
    float dtp = (dtr > 15.f) ? dtr : log1pf(__expf(dtr));
    sdtp[tid] = dtp;
    float Ar = -__expf(A_log[tid]);
    dAr[(size_t)r * NHEADS + tid] = __expf(dtp * Ar);
  }
  if (tid < 128) {
    int ch = D_INNER + tid;   // conv channel 1536..1663
    float v = row[2 * D_INNER + tid] * conv_w[ch * 4 + 3] + conv_b[ch];
    siluBC[(size_t)r * 128 + tid] = silu_f(v);
  }
  __syncthreads();
#pragma unroll
  for (int i = 0; i < 6; i++) {
    int c = tid + i * 256;           // 0..1535
    float xv = silu_f(row[D_INNER + c] * conv_w[c * 4 + 3] + conv_b[c]);
    int h = c >> 6;
    coefX[(size_t)r * D_INNER + c] = sdtp[h] * xv;
    dxX[(size_t)r * D_INNER + c]  = Dp[h] * xv;
  }
}

// ---------------- scan: barrier-free, 2-deep register prefetch, nontemporal state stores ----------------
__global__ __launch_bounds__(256) void scan2_kernel(
    const float* __restrict__ siluBC,  // ROWS x 128  (B then C)
    const float* __restrict__ coefX,   // ROWS x 1536
    const float* __restrict__ dAr,     // ROWS x 24
    const float* __restrict__ dxX,     // ROWS x 1536
    float* __restrict__ states,        // ROWS x 24 x 64 x 64
    float* __restrict__ y_raw)         // ROWS x D_INNER
{
  int g = blockIdx.x;
  int bh = g >> 2, qp = g & 3;
  int b = bh / NHEADS, hh = bh - b * NHEADS;
  int tid = threadIdx.x;
  int pp = tid >> 4, nq = tid & 15;
  int n0 = nq * 4;
  int p  = qp * 16 + pp;
  int chp = hh * HEADDIM + p;

  f32x4 h4 = {0.f, 0.f, 0.f, 0.f};

  f32x4 aB, aC, bB, bC;
  float aCo, adA, aDx, bCo, bdA, bDx;
  {
    int r = b;                          // t=0
    aB  = *(const f32x4*)(siluBC + (size_t)r * 128 + n0);
    aC  = *(const f32x4*)(siluBC + (size_t)r * 128 + 64 + n0);
    aCo = coefX[(size_t)r * D_INNER + chp];
    adA = dAr[(size_t)r * NHEADS + hh];
    aDx = dxX[(size_t)r * D_INNER + chp];
    r = BATCH + b;                      // t=1
    bB  = *(const f32x4*)(siluBC + (size_t)r * 128 + n0);
    bC  = *(const f32x4*)(siluBC + (size_t)r * 128 + 64 + n0);
    bCo = coefX[(size_t)r * D_INNER + chp];
    bdA = dAr[(size_t)r * NHEADS + hh];
    bDx = dxX[(size_t)r * D_INNER + chp];
  }

  for (int t = 0; t < SEQ_LEN; t += 2) {
    // even step: consume stage A, refill A for t+2
    {
      int r = t * BATCH + b;
#pragma unroll
      for (int q = 0; q < 4; q++) h4[q] = h4[q] * adA + aCo * aB[q];
      float* sp = states + ((size_t)r * NHEADS + hh) * 4096 + (size_t)p * 64 + n0;
      __builtin_nontemporal_store(h4, (f32x4*)sp);
      float acc = h4[0] * aC[0] + h4[1] * aC[1] + h4[2] * aC[2] + h4[3] * aC[3];
      acc += __shfl_xor(acc, 1);
      acc += __shfl_xor(acc, 2);
      acc += __shfl_xor(acc, 4);
      acc += __shfl_xor(acc, 8);
      if (nq == 0) y_raw[(size_t)r * D_INNER + chp] = acc + aDx;
      if (t + 2 < SEQ_LEN) {
        int rn = (t + 2) * BATCH + b;
        aB  = *(const f32x4*)(siluBC + (size_t)rn * 128 + n0);
        aC  = *(const f32x4*)(siluBC + (size_t)rn * 128 + 64 + n0);
        aCo = coefX[(size_t)rn * D_INNER + chp];
        adA = dAr[(size_t)rn * NHEADS + hh];
        aDx = dxX[(size_t)rn * D_INNER + chp];
      }
    }
    // odd step: consume stage B, refill B for t+3
    {
      int r = (t + 1) * BATCH + b;
#pragma unroll
      for (int q = 0; q < 4; q++) h4[q] = h4[q] * bdA + bCo * bB[q];
      float* sp = states + ((size_t)r * NHEADS + hh) * 4096 + (size_t)p * 64 + n0;
      __builtin_nontemporal_store(h4, (f32x4*)sp);
      float acc = h4[0] * bC[0] + h4[1] * bC[1] + h4[2] * bC[2] + h4[3] * bC[3];
      acc += __shfl_xor(acc, 1);
      acc += __shfl_xor(acc, 2);
      acc += __shfl_xor(acc, 4);
      acc += __shfl_xor(acc, 8);
      if (nq == 0) y_raw[(size_t)r * D_INNER + chp] = acc + bDx;
      if (t + 3 < SEQ_LEN) {
        int rn = (t + 3) * BATCH + b;
        bB  = *(const f32x4*)(siluBC + (size_t)rn * 128 + n0);
        bC  = *(const f32x4*)(siluBC + (size_t)rn * 128 + 64 + n0);
        bCo = coefX[(size_t)rn * D_INNER + chp];
        bdA = dAr[(size_t)rn * NHEADS + hh];
        bDx = dxX[(size_t)rn * D_INNER + chp];
      }
    }
  }
}

// ---------------- gate (silu(z)) + RMSNorm + cast to f16 ----------------
__global__ __launch_bounds__(256) void gate_norm_kernel(
    const float* __restrict__ zx, const float* __restrict__ y_raw,
    const float* __restrict__ norm_w, _Float16* __restrict__ yh)
{
  int r = blockIdx.x;
  const float* z = zx + (size_t)r * ZXLD;
  const float* y = y_raw + (size_t)r * D_INNER;
  float v[6];
  float ss = 0.f;
#pragma unroll
  for (int i = 0; i < 6; i++) {
    int c = threadIdx.x + i * 256;
    float w = y[c] * silu_f(z[c]);
    v[i] = w;
    ss += w * w;
  }
#pragma unroll
  for (int o = 32; o > 0; o >>= 1) ss += __shfl_xor(ss, o);
  __shared__ float red[4];
  if ((threadIdx.x & 63) == 0) red[threadIdx.x >> 6] = ss;
  __syncthreads();
  float tot = red[0] + red[1] + red[2] + red[3];
  float scale = rsqrtf(tot / (float)D_INNER + 1e-5f);
#pragma unroll
  for (int i = 0; i < 6; i++) {
    int c = threadIdx.x + i * 256;
    yh[(size_t)r * D_INNER + c] = (_Float16)(v[i] * scale * norm_w[c]);
  }
}

extern "C" void kernel_launch(void* const* d_in, const int* in_sizes, int n_in,
                              void* d_out, int out_size, void* d_ws, size_t ws_size,
                              hipStream_t stream)
{
  (void)in_sizes; (void)n_in; (void)out_size; (void)ws_size;
  const float* seq     = (const float*)d_in[0];
  const float* W_in    = (const float*)d_in[1];
  const float* conv_w  = (const float*)d_in[2];
  const float* conv_b  = (const float*)d_in[3];
  const float* dt_bias = (const float*)d_in[4];
  const float* A_log   = (const float*)d_in[5];
  const float* Dp      = (const float*)d_in[6];
  const float* norm_w  = (const float*)d_in[7];
  const float* W_out   = (const float*)d_in[8];

  float* out    = (float*)d_out;                                  // (256,8,768)
  float* states = out + (size_t)SEQ_LEN * BATCH * D_MODEL;        // (256,8,24,64,64)

  char* ws = (char*)d_ws;
  size_t off = 0;
  auto alloc = [&](size_t bytes) -> void* {
    void* p = ws + off;
    off = (off + bytes + 255) & ~(size_t)255;
    return p;
  };
  float*    zx     = (float*)   alloc((size_t)ROWS * ZXLD * 4);
  float*    y_raw  = (float*)   alloc((size_t)ROWS * D_INNER * 4);
  _Float16* seqh   = (_Float16*)alloc((size_t)ROWS * D_MODEL * 2);
  _Float16* WinT   = (_Float16*)alloc((size_t)ZXLD * D_MODEL * 2);
  _Float16* WoutT  = (_Float16*)alloc((size_t)D_MODEL * D_INNER * 2);
  _Float16* yh     = (_Float16*)alloc((size_t)ROWS * D_INNER * 2);
  float*    siluBC = (float*)   alloc((size_t)ROWS * 128 * 4);
  float*    coefX  = (float*)   alloc((size_t)ROWS * D_INNER * 4);
  float*    dxX    = (float*)   alloc((size_t)ROWS * D_INNER * 4);
  float*    dAr    = (float*)   alloc((size_t)ROWS * NHEADS * 4);

  // 1) fused cast + transposes (one dispatch, fully parallel)
  pre_fused_kernel<<<CAST_BLKS + TW1_BLKS + TW2_BLKS, 256, 0, stream>>>(
      seq, seqh, W_in, WinT, W_out, WoutT);

  // 2) in-projection GEMM: zx = seq @ W_in   (M=2048, N=3328(pad), K=768)
  gemm_f16_glds<<<dim3(ROWS / 128, ZXLD / 128), 256, 0, stream>>>(
      seqh, WinT, zx, ROWS, ZXLD, D_MODEL);

  // 3) prep (parallel activations + per-step scalars)
  prep_kernel<<<ROWS, 256, 0, stream>>>(
      zx, conv_w, conv_b, dt_bias, A_log, Dp, siluBC, coefX, dxX, dAr);

  // 4) barrier-free scan (writes all states + raw y)
  scan2_kernel<<<BATCH * NHEADS * 4, 256, 0, stream>>>(
      siluBC, coefX, dAr, dxX, states, y_raw);

  // 5) gate + RMSNorm -> f16
  gate_norm_kernel<<<ROWS, 256, 0, stream>>>(zx, y_raw, norm_w, yh);

  // 6) out-projection GEMM: out = yh @ W_out  (M=2048, N=768, K=1536)
  gemm_f16_glds<<<dim3(ROWS / 128, D_MODEL / 128), 256, 0, stream>>>(
      yh, WoutT, out, ROWS, D_MODEL, D_INNER);
}